// Round 4
// baseline (292.334 us; speedup 1.0000x reference)
//
#include <hip/hip_runtime.h>
#include <cmath>

#define B_SZ 512
#define D_SZ 128
#define K_SZ 4096
#define NDATA 500000
#define TEMP 0.07f
#define MOM 0.5f
#define EPSN 1e-12f
#define SPLIT 4

#define NCOPY_BLK 1024
#define NGATHER_BLK (B_SZ * SPLIT)   // 2048
#define NFUSED_BLK (NCOPY_BLK + NGATHER_BLK)  // 3072, interleaved mod 3

typedef float f32x4 __attribute__((ext_vector_type(4)));

// ---------------- kernel A: normalize s,t + pos logits ----------------
__global__ void knorm(const float* __restrict__ s_in, const float* __restrict__ t_in,
                      float* __restrict__ s_n, float* __restrict__ t_n,
                      float* __restrict__ pos) {
    int b = blockIdx.x;
    int l = threadIdx.x;  // 64 lanes, each handles 2 floats
    float2 sv = ((const float2*)(s_in + b * D_SZ))[l];
    float2 tv = ((const float2*)(t_in + b * D_SZ))[l];
    float ss = sv.x * sv.x + sv.y * sv.y;
    float tt = tv.x * tv.x + tv.y * tv.y;
    for (int m = 1; m < 64; m <<= 1) {
        ss += __shfl_xor(ss, m, 64);
        tt += __shfl_xor(tt, m, 64);
    }
    float sinv = 1.0f / fmaxf(sqrtf(ss), EPSN);
    float tinv = 1.0f / fmaxf(sqrtf(tt), EPSN);
    float2 sn = {sv.x * sinv, sv.y * sinv};
    float2 tn = {tv.x * tinv, tv.y * tinv};
    ((float2*)(s_n + b * D_SZ))[l] = sn;
    ((float2*)(t_n + b * D_SZ))[l] = tn;
    float d = sn.x * tn.x + sn.y * tn.y;
    for (int m = 1; m < 64; m <<= 1) d += __shfl_xor(d, m, 64);
    if (l == 0) pos[b] = d * (1.0f / TEMP);
}

// ---------------- fused kernel: copy (HBM-bound) || gather-LSE (L3-bound) ----------------
// blockIdx.x % 3 == 0 -> copy role (NCOPY_BLK blocks)
// else               -> gather role (NGATHER_BLK blocks)
__global__ __launch_bounds__(256) void kfused(const float* __restrict__ bank,
                                              float* __restrict__ out /* d_out */,
                                              const int* __restrict__ negidx,
                                              const float* __restrict__ s_n,
                                              float2* __restrict__ partials) {
    const int r = blockIdx.x % 3;
    const int q = blockIdx.x / 3;
    const int tid = threadIdx.x;

    if (r == 0) {
        // ---- copy role: out[1+i] = bank[i], aligned loads + aligned NT stores ----
        const long long total = (long long)NDATA * D_SZ;  // 64,000,000
        const long long NV = total / 4;                   // 16,000,000 src vectors
        long long t = q * 256LL + tid;
        const long long nthr = NCOPY_BLK * 256LL;
        const f32x4* src4 = (const f32x4*)bank;
        f32x4* out4 = (f32x4*)out;  // out4[j] = out[4j..4j+3], 16B aligned
        if (t == 0) {
            out[1] = bank[0]; out[2] = bank[1]; out[3] = bank[2];
            out[total] = bank[total - 1];
        }
        // out4[j] = {bank[4j-1], bank[4j], bank[4j+1], bank[4j+2]}, j in [1, NV)
        for (long long j = 1 + t; j < NV; j += nthr) {
            f32x4 v = src4[j];                 // aligned 16B load
            float p = bank[4 * j - 1];         // scalar load, L1-resident line
            f32x4 w; w.x = p; w.y = v.x; w.z = v.y; w.w = v.z;
            __builtin_nontemporal_store(w, out4 + j);  // aligned 16B NT store
        }
    } else {
        // ---- gather role ----
        const int g = 2 * q + (r - 1);       // [0, 2048)
        const int b = g >> 2;
        const int split = g & 3;
        __shared__ float s_lds[D_SZ];
        if (tid < 32) ((float4*)s_lds)[tid] = ((const float4*)(s_n + b * D_SZ))[tid];
        __syncthreads();
        const int lane = tid & 31;
        const int grp = tid >> 5;  // 8 groups of 32 lanes
        float4 sv = ((const float4*)s_lds)[lane];
        float m = -INFINITY, ssum = 0.0f;
        const int base = b * K_SZ + split * (K_SZ / SPLIT);
        const int iters = (K_SZ / SPLIT) / 16;  // 64, 2 rows per group per iter
        for (int it = 0; it < iters; ++it) {
            int k = it * 16 + grp * 2;
            int idx0 = negidx[base + k];
            int idx1 = negidx[base + k + 1];
            float4 v0 = ((const float4*)(bank + (long long)idx0 * D_SZ))[lane];
            float4 v1 = ((const float4*)(bank + (long long)idx1 * D_SZ))[lane];
            float d0 = v0.x * sv.x + v0.y * sv.y + v0.z * sv.z + v0.w * sv.w;
            float d1 = v1.x * sv.x + v1.y * sv.y + v1.z * sv.z + v1.w * sv.w;
            d0 += __shfl_xor(d0, 1, 32);
            d1 += __shfl_xor(d1, 1, 32);
            d0 += __shfl_xor(d0, 2, 32);
            d1 += __shfl_xor(d1, 2, 32);
            d0 += __shfl_xor(d0, 4, 32);
            d1 += __shfl_xor(d1, 4, 32);
            d0 += __shfl_xor(d0, 8, 32);
            d1 += __shfl_xor(d1, 8, 32);
            d0 += __shfl_xor(d0, 16, 32);
            d1 += __shfl_xor(d1, 16, 32);
            d0 *= (1.0f / TEMP);
            d1 *= (1.0f / TEMP);
            float mn = fmaxf(m, fmaxf(d0, d1));
            ssum = ssum * __expf(m - mn) + __expf(d0 - mn) + __expf(d1 - mn);
            m = mn;
        }
        __shared__ float2 gp[8];
        if (lane == 0) gp[grp] = make_float2(m, ssum);
        __syncthreads();
        if (tid == 0) {
            float M = gp[0].x, S = gp[0].y;
            for (int gg = 1; gg < 8; ++gg) {
                float mg = gp[gg].x, sg = gp[gg].y;
                float mn = fmaxf(M, mg);
                S = S * __expf(M - mn) + sg * __expf(mg - mn);
                M = mn;
            }
            partials[b * SPLIT + split] = make_float2(M, S);
        }
    }
}

// ---------------- kernel C: momentum scatter-update (last-wins) ----------------
__global__ void kupdate(const int* __restrict__ indices, const float* __restrict__ bank,
                        const float* __restrict__ t_n, float* __restrict__ outBank /* d_out+1 */) {
    int j = blockIdx.x;
    int l = threadIdx.x;  // 64
    int idx = indices[j];
    // numpy fancy-assignment semantics: last occurrence wins
    for (int j2 = j + 1; j2 < B_SZ; ++j2)
        if (indices[j2] == idx) return;
    float2 bv = ((const float2*)(bank + (long long)idx * D_SZ))[l];
    float2 tv = ((const float2*)(t_n + j * D_SZ))[l];
    float2 u = {MOM * bv.x + (1.0f - MOM) * tv.x, MOM * bv.y + (1.0f - MOM) * tv.y};
    float ss = u.x * u.x + u.y * u.y;
    for (int m = 1; m < 64; m <<= 1) ss += __shfl_xor(ss, m, 64);
    float inv = 1.0f / fmaxf(sqrtf(ss), EPSN);
    float* dst = outBank + (long long)idx * D_SZ + l * 2;  // 4B-aligned only
    dst[0] = u.x * inv;
    dst[1] = u.y * inv;
}

// ---------------- kernel E: combine partials -> loss ----------------
__global__ void kfinal(const float2* __restrict__ partials, const float* __restrict__ pos,
                       float* __restrict__ out) {
    __shared__ float red[B_SZ];
    int t = threadIdx.x;  // 512 threads, one per batch row
    float M = -INFINITY, S = 0.0f;
    for (int p = 0; p < SPLIT; ++p) {
        float2 ms = partials[t * SPLIT + p];
        float mn = fmaxf(M, ms.x);
        S = S * __expf(M - mn) + ms.y * __expf(ms.x - mn);
        M = mn;
    }
    float pl = pos[t];
    float mn = fmaxf(M, pl);
    S = S * __expf(M - mn) + __expf(pl - mn);
    M = mn;
    float lse = M + logf(S);
    red[t] = lse - pl;
    __syncthreads();
    for (int off = 256; off > 0; off >>= 1) {
        if (t < off) red[t] += red[t + off];
        __syncthreads();
    }
    if (t == 0) out[0] = red[0] * (1.0f / (float)B_SZ);
}

extern "C" void kernel_launch(void* const* d_in, const int* in_sizes, int n_in,
                              void* d_out, int out_size, void* d_ws, size_t ws_size,
                              hipStream_t stream) {
    const float* student = (const float*)d_in[0];
    const float* teacher = (const float*)d_in[1];
    const float* bank    = (const float*)d_in[2];
    const int*   indices = (const int*)d_in[3];
    const int*   negidx  = (const int*)d_in[4];
    float* out = (float*)d_out;

    // workspace layout (floats)
    float* ws = (float*)d_ws;
    float* s_n      = ws;                       // 512*128
    float* t_n      = s_n + B_SZ * D_SZ;        // 512*128
    float* pos      = t_n + B_SZ * D_SZ;        // 512
    float2* partials = (float2*)(pos + B_SZ);   // 512*SPLIT float2

    // 1) normalize + pos logits (tiny)
    knorm<<<B_SZ, 64, 0, stream>>>(student, teacher, s_n, t_n, pos);
    // 2) fused: bank copy (HBM) co-scheduled with negative gather+LSE (L3)
    kfused<<<NFUSED_BLK, 256, 0, stream>>>(bank, out, negidx, s_n, partials);
    // 3) momentum scatter-update of indexed rows (after copy done)
    kupdate<<<B_SZ, 64, 0, stream>>>(indices, bank, t_n, out + 1);
    // 4) final loss (tiny)
    kfinal<<<1, B_SZ, 0, stream>>>(partials, pos, out);
}